// Round 5
// baseline (156.848 us; speedup 1.0000x reference)
//
#include <hip/hip_runtime.h>
#include <hip/hip_bf16.h>
#include <math.h>

#define NQ   10
#define DIM  1024     // 2^NQ
#define NL   4
#define INF  512
#define OUTF 64
#define MBATCH 4096

typedef _Float16 half8 __attribute__((ext_vector_type(8)));
typedef float f32x4 __attribute__((ext_vector_type(4)));
typedef float f32x2 __attribute__((ext_vector_type(2)));

// ws layout (bytes)
#define WS_H16  0
#define WS_X16  (8u * 1024u * 1024u)
#define WS_W16  (12u * 1024u * 1024u)
#define WS_SU   (13u * 1024u * 1024u)

#if __has_builtin(__builtin_amdgcn_permlane16_swap) && __has_builtin(__builtin_amdgcn_permlane32_swap)
#define HAVE_PL 1
#else
#define HAVE_PL 0
#endif

// ===========================================================================
// Compile-time GF(2) layout tracking (verified round 4).
// ===========================================================================
constexpr int fstep(int j, int r) {
    for (int w2 = NQ - 1; w2 >= 0; --w2) {
        const int cb = 9 - w2;
        const int tb = 9 - ((w2 + r) % NQ);
        j ^= ((j >> cb) & 1) << tb;
    }
    return j;
}
constexpr int ifstep(int j, int r) {
    for (int w2 = 0; w2 < NQ; ++w2) {
        const int cb = 9 - w2;
        const int tb = 9 - ((w2 + r) % NQ);
        j ^= ((j >> cb) & 1) << tb;
    }
    return j;
}
constexpr int sigma_fwd(int l, int x) {
    for (int t = l - 1; t >= 0; --t) x = fstep(x, t + 1);
    return x;
}
constexpr int sigma_inv(int l, int s) {
    for (int t = 0; t < l; ++t) s = ifstep(s, t + 1);
    return s;
}
constexpr int gate_m(int l, int b) { return sigma_fwd(l, 1 << b); }
constexpr int gate_g(int l, int b) {
    int g = 0;
    for (int j = 0; j < NQ; ++j)
        if ((sigma_inv(l, 1 << j) >> b) & 1) g |= 1 << j;
    return g;
}
struct QM { int v[NQ]; };
constexpr QM make_qm() {
    QM q{};
    for (int w = 0; w < NQ; ++w) {
        const int B = 9 - w;
        int m = 0;
        for (int j = 0; j < NQ; ++j)
            if ((sigma_inv(NL, 1 << j) >> B) & 1) m |= 1 << j;
        q.v[w] = m;
    }
    return q;
}
constexpr QM QMASKS = make_qm();

// ===========================================================================
// Setup + GEMM (unchanged, verified rounds 3-4)
// ===========================================================================
__global__ __launch_bounds__(256) void setup_kernel(
    const float* __restrict__ x, const float* __restrict__ w,
    const float* __restrict__ qw, _Float16* __restrict__ x16,
    _Float16* __restrict__ w16, float* __restrict__ su)
{
    const int bid = blockIdx.x;
    const int tid = threadIdx.x;
    if (bid < 1024) {
        const int base = bid * 2048 + tid * 8;
        float4 a = *reinterpret_cast<const float4*>(x + base);
        float4 b = *reinterpret_cast<const float4*>(x + base + 4);
        half8 o = {(_Float16)a.x, (_Float16)a.y, (_Float16)a.z, (_Float16)a.w,
                   (_Float16)b.x, (_Float16)b.y, (_Float16)b.z, (_Float16)b.w};
        *reinterpret_cast<half8*>(x16 + base) = o;
    } else if (bid < 1280) {
        const int base = (bid - 1024) * 2048 + tid * 8;
        float4 a = *reinterpret_cast<const float4*>(w + base);
        float4 b = *reinterpret_cast<const float4*>(w + base + 4);
        half8 o = {(_Float16)a.x, (_Float16)a.y, (_Float16)a.z, (_Float16)a.w,
                   (_Float16)b.x, (_Float16)b.y, (_Float16)b.z, (_Float16)b.w};
        *reinterpret_cast<half8*>(w16 + base) = o;
    } else {
        if (tid < NL * NQ) {
            float phi = qw[tid * 3 + 0], theta = qw[tid * 3 + 1], omega = qw[tid * 3 + 2];
            float st, ct; sincosf(0.5f * theta, &st, &ct);
            float spm, cpm; sincosf(0.5f * (phi - omega), &spm, &cpm);
            float spp, cpp; sincosf(0.5f * (phi + omega), &spp, &cpp);
            float* o = su + tid * 8;
            o[0] =  cpp * ct; o[1] = -spp * ct;
            o[2] = -cpm * st; o[3] = -spm * st;
            o[4] =  cpm * st; o[5] = -spm * st;
            o[6] =  cpp * ct; o[7] =  spp * ct;
        }
    }
}

__global__ __launch_bounds__(256) void gemm16_kernel(
    const _Float16* __restrict__ X, const _Float16* __restrict__ W,
    const float* __restrict__ bias, _Float16* __restrict__ H)
{
    constexpr int BM = 128, BN = 64, BK = 32, LDP = BK + 8;
    __shared__ _Float16 As[BM][LDP];
    __shared__ _Float16 Bs[BN][LDP];

    const int tid = threadIdx.x;
    const int wave = tid >> 6, lane = tid & 63;
    const int wm = wave >> 1, wn = wave & 1;
    const int l15 = lane & 15, lk = (lane >> 4) * 8;

    const int arow = tid >> 1, ahalf = tid & 1;
    const int brow = tid & 63, bseg = tid >> 6;

    const _Float16* ag = X + (size_t)(blockIdx.x * BM + arow) * INF + ahalf * 16;
    const _Float16* bg = W + (size_t)(blockIdx.y * BN + brow) * INF + bseg * 8;

    f32x4 acc[4][2] = {};

    for (int k0 = 0; k0 < INF; k0 += BK) {
        half8 av0 = *reinterpret_cast<const half8*>(ag + k0);
        half8 av1 = *reinterpret_cast<const half8*>(ag + k0 + 8);
        half8 bv  = *reinterpret_cast<const half8*>(bg + k0);
        __syncthreads();
        *reinterpret_cast<half8*>(&As[arow][ahalf * 16])     = av0;
        *reinterpret_cast<half8*>(&As[arow][ahalf * 16 + 8]) = av1;
        *reinterpret_cast<half8*>(&Bs[brow][bseg * 8])       = bv;
        __syncthreads();
        half8 bfr0 = *reinterpret_cast<const half8*>(&Bs[wn * 32 + l15][lk]);
        half8 bfr1 = *reinterpret_cast<const half8*>(&Bs[wn * 32 + 16 + l15][lk]);
#pragma unroll
        for (int mi = 0; mi < 4; ++mi) {
            half8 afr = *reinterpret_cast<const half8*>(&As[wm * 64 + mi * 16 + l15][lk]);
            acc[mi][0] = __builtin_amdgcn_mfma_f32_16x16x32_f16(afr, bfr0, acc[mi][0], 0, 0, 0);
            acc[mi][1] = __builtin_amdgcn_mfma_f32_16x16x32_f16(afr, bfr1, acc[mi][1], 0, 0, 0);
        }
    }

    const int crow0 = blockIdx.x * BM + wm * 64;
    const int ccol0 = blockIdx.y * BN + wn * 32;
#pragma unroll
    for (int ni = 0; ni < 2; ++ni) {
        const int col = ccol0 + ni * 16 + l15;
        const float bb = bias[col];
#pragma unroll
        for (int mi = 0; mi < 4; ++mi) {
#pragma unroll
            for (int r = 0; r < 4; ++r) {
                const int row = crow0 + mi * 16 + (lane >> 4) * 4 + r;
                const float o = fmaxf(acc[mi][ni][r] + bb, 0.f);
                H[(size_t)row * DIM + col] = (_Float16)o;
            }
        }
    }
}

// ===========================================================================
// Cross-lane xor exchange, compile-time routed:
//   DPP: {1,2,3,7,8,15}; permlane16/32_swap (gfx950 VALU): 16/32/48 + DPP
//   residue; ds_swizzle: other masks <32; ds_bpermute: the rest.
// permlane semantics: v_permlaneN_swap(a,b) swaps a's hi rows with b's lo
// rows; with a=b=v, partner(v^N) = (lane&N) ? out[0] : out[1].
// ===========================================================================
constexpr bool dpp_ok(int m) {
    return m == 0 || m == 1 || m == 2 || m == 3 || m == 7 || m == 8 || m == 15;
}
constexpr int dpp_ctrl(int m) {
    return m == 1 ? 0xB1 : m == 2 ? 0x4E : m == 3 ? 0x1B :
           m == 7 ? 0x141 : m == 8 ? 0x128 : 0x140;   // 15 -> row_mirror
}

template<int MHI>
__device__ __forceinline__ int lxi(int v, int lane) {
    if constexpr (MHI == 0)
        return v;
    else if constexpr (dpp_ok(MHI))
        return __builtin_amdgcn_mov_dpp(v, dpp_ctrl(MHI), 0xF, 0xF, false);
#if HAVE_PL
    else if constexpr ((MHI & 32) && dpp_ok(MHI & 15)) {
        auto q = __builtin_amdgcn_permlane32_swap(v, v, false, false);
        const int r = (lane & 32) ? q[0] : q[1];
        return lxi<MHI & 31>(r, lane);
    }
    else if constexpr ((MHI & 16) && dpp_ok(MHI & 15)) {
        auto q = __builtin_amdgcn_permlane16_swap(v, v, false, false);
        const int r = (lane & 16) ? q[0] : q[1];
        return lxi<MHI & 15>(r, lane);
    }
#endif
    else if constexpr (MHI < 32)
        return __builtin_amdgcn_ds_swizzle(v, 0x1F | (MHI << 10));
    else
        return __builtin_amdgcn_ds_bpermute((lane ^ MHI) << 2, v);
}

template<int MHI>
__device__ __forceinline__ float lxf(float v, int lane) {
    return __int_as_float(lxi<MHI>(__float_as_int(v), lane));
}

// butterfly allreduce (sum) across 64 lanes via cheap exchanges
__device__ __forceinline__ float allred(float v, int lane) {
    v += lxf<1>(v, lane);
    v += lxf<2>(v, lane);
    v += lxf<4>(v, lane);
    v += lxf<8>(v, lane);
    v += lxf<16>(v, lane);
    v += lxf<32>(v, lane);
    return v;
}

// ===========================================================================
// One gate (layer L, wire W), one row. State rr/ii[8] f32x2 (amp k: bit0 of
// k selects .x/.y). Verified structure from round 4.
// ===========================================================================
template<int L, int W>
__device__ __forceinline__ void apply_gate(f32x2 rr[8], f32x2 ii[8],
                                           const float* __restrict__ su, int lane)
{
    constexpr int b   = 9 - W;
    constexpr int m   = gate_m(L, b);
    constexpr int g   = gate_g(L, b);
    constexpr int MHI = m >> 4, MLO = m & 15;
    constexpr int GHI = g >> 4, GLO = g & 15;

    const float4 ua = *reinterpret_cast<const float4*>(su + (L * NQ + W) * 8);
    const float4 ub = *reinterpret_cast<const float4*>(su + (L * NQ + W) * 8 + 4);
    const bool hl = __builtin_popcount(lane & GHI) & 1;

    const float cmr0 = hl ? ub.z : ua.x, cmi0 = hl ? ub.w : ua.y;
    const float cpr0 = hl ? ub.x : ua.z, cpi0 = hl ? ub.y : ua.w;
    const float cmr1 = hl ? ua.x : ub.z, cmi1 = hl ? ua.y : ub.w;
    const float cpr1 = hl ? ua.z : ub.x, cpi1 = hl ? ua.w : ub.y;

    float pr[16], pi[16];
#pragma unroll
    for (int k = 0; k < 16; ++k) {
        const int kp = k ^ MLO;
        const float vr = (kp & 1) ? rr[kp >> 1].y : rr[kp >> 1].x;
        const float vi = (kp & 1) ? ii[kp >> 1].y : ii[kp >> 1].x;
        pr[k] = lxf<MHI>(vr, lane);
        pi[k] = lxf<MHI>(vi, lane);
    }
#pragma unroll
    for (int j = 0; j < 8; ++j) {
        const int k0 = 2 * j, k1 = 2 * j + 1;
        const int h0 = __builtin_popcount(k0 & GLO) & 1;
        const int h1 = __builtin_popcount(k1 & GLO) & 1;
        f32x2 CMR, CMI, CPR, CPI, PR, PI;
        CMR.x = h0 ? cmr1 : cmr0;  CMR.y = h1 ? cmr1 : cmr0;
        CMI.x = h0 ? cmi1 : cmi0;  CMI.y = h1 ? cmi1 : cmi0;
        CPR.x = h0 ? cpr1 : cpr0;  CPR.y = h1 ? cpr1 : cpr0;
        CPI.x = h0 ? cpi1 : cpi0;  CPI.y = h1 ? cpi1 : cpi0;
        PR.x = pr[k0]; PR.y = pr[k1];
        PI.x = pi[k0]; PI.y = pi[k1];
        const f32x2 R = rr[j], I = ii[j];
        rr[j] = R * CMR - I * CMI + PR * CPR - PI * CPI;
        ii[j] = I * CMR + R * CMI + PI * CPR + PR * CPI;
    }
}

// two rows interleaved at gate granularity (coeff logic CSE'd by compiler)
template<int L>
__device__ __forceinline__ void apply_layer2(f32x2 rA[8], f32x2 iA[8],
                                             f32x2 rB[8], f32x2 iB[8],
                                             const float* __restrict__ su, int lane)
{
    apply_gate<L, 0>(rA, iA, su, lane); apply_gate<L, 0>(rB, iB, su, lane);
    apply_gate<L, 1>(rA, iA, su, lane); apply_gate<L, 1>(rB, iB, su, lane);
    apply_gate<L, 2>(rA, iA, su, lane); apply_gate<L, 2>(rB, iB, su, lane);
    apply_gate<L, 3>(rA, iA, su, lane); apply_gate<L, 3>(rB, iB, su, lane);
    apply_gate<L, 4>(rA, iA, su, lane); apply_gate<L, 4>(rB, iB, su, lane);
    apply_gate<L, 5>(rA, iA, su, lane); apply_gate<L, 5>(rB, iB, su, lane);
    apply_gate<L, 6>(rA, iA, su, lane); apply_gate<L, 6>(rB, iB, su, lane);
    apply_gate<L, 7>(rA, iA, su, lane); apply_gate<L, 7>(rB, iB, su, lane);
    apply_gate<L, 8>(rA, iA, su, lane); apply_gate<L, 8>(rB, iB, su, lane);
    apply_gate<L, 9>(rA, iA, su, lane); apply_gate<L, 9>(rB, iB, su, lane);
}

__device__ __forceinline__ void load_row(const _Float16* __restrict__ hr,
                                         f32x2 rr[8], f32x2 ii[8], float& nrm,
                                         int lane)
{
    half8 h0 = *reinterpret_cast<const half8*>(hr);
    half8 h1 = *reinterpret_cast<const half8*>(hr + 8);
#pragma unroll
    for (int j = 0; j < 4; ++j) {
        rr[j].x     = (float)h0[2 * j]; rr[j].y     = (float)h0[2 * j + 1];
        rr[j + 4].x = (float)h1[2 * j]; rr[j + 4].y = (float)h1[2 * j + 1];
        ii[j]     = f32x2{0.f, 0.f};
        ii[j + 4] = f32x2{0.f, 0.f};
    }
    f32x2 n2 = f32x2{0.f, 0.f};
#pragma unroll
    for (int j = 0; j < 8; ++j) n2 += rr[j] * rr[j];
    nrm = allred(n2.x + n2.y, lane);
}

__device__ __forceinline__ void expvals(const f32x2 rr[8], const f32x2 ii[8],
                                        float inv_nrm, float z[NQ], int lane)
{
    f32x2 P[8];
#pragma unroll
    for (int j = 0; j < 8; ++j) P[j] = rr[j] * rr[j] + ii[j] * ii[j];
#pragma unroll
    for (int w = 0; w < NQ; ++w) {
        const int q = QMASKS.v[w];
        const int qhi = q >> 4, qlo = q & 15;
        float zl = 0.f;
#pragma unroll
        for (int j = 0; j < 8; ++j) {
            const float s0 = (__builtin_popcount((2 * j) & qlo) & 1) ? -1.f : 1.f;
            const float s1 = (__builtin_popcount((2 * j + 1) & qlo) & 1) ? -1.f : 1.f;
            zl += s0 * P[j].x;
            zl += s1 * P[j].y;
        }
        if (__builtin_popcount(lane & qhi) & 1) zl = -zl;
        z[w] = allred(zl, lane) * inv_nrm;
    }
}

// ===========================================================================
// Kernel 2: one wave handles TWO batch rows (ILP); 4 waves/block.
// ===========================================================================
__global__ __launch_bounds__(256) void quantum_kernel(
    const _Float16* __restrict__ Hbuf, const float* __restrict__ sug,
    const float* __restrict__ W_post, const float* __restrict__ b_post,
    float* __restrict__ out)
{
    const int lane = threadIdx.x;
    const int rowA = (blockIdx.x * 4 + threadIdx.y) * 2;
    const int rowB = rowA + 1;

    f32x2 rA[8], iA[8], rB[8], iB[8];
    float nA, nB;
    load_row(Hbuf + (size_t)rowA * DIM + (lane << 4), rA, iA, nA, lane);
    load_row(Hbuf + (size_t)rowB * DIM + (lane << 4), rB, iB, nB, lane);
    const float invA = 1.0f / nA;
    const float invB = 1.0f / nB;

    apply_layer2<0>(rA, iA, rB, iB, sug, lane);
    apply_layer2<1>(rA, iA, rB, iB, sug, lane);
    apply_layer2<2>(rA, iA, rB, iB, sug, lane);
    apply_layer2<3>(rA, iA, rB, iB, sug, lane);

    float zA[NQ], zB[NQ];
    expvals(rA, iA, invA, zA, lane);
    expvals(rB, iB, invB, zB, lane);

    // post-GEMM (W_post row loaded once, shared by both rows)
    float wv[NQ];
#pragma unroll
    for (int w = 0; w < NQ; ++w) wv[w] = W_post[lane * NQ + w];
    const float bb = b_post[lane];
    float oA = bb, oB = bb;
#pragma unroll
    for (int w = 0; w < NQ; ++w) {
        oA = fmaf(zA[w], wv[w], oA);
        oB = fmaf(zB[w], wv[w], oB);
    }
    out[(size_t)rowA * OUTF + lane] = oA;
    out[(size_t)rowB * OUTF + lane] = oB;
}

extern "C" void kernel_launch(void* const* d_in, const int* in_sizes, int n_in,
                              void* d_out, int out_size, void* d_ws, size_t ws_size,
                              hipStream_t stream) {
    const float* x      = (const float*)d_in[0];
    const float* W_pre  = (const float*)d_in[1];
    const float* b_pre  = (const float*)d_in[2];
    const float* qw     = (const float*)d_in[3];
    const float* W_post = (const float*)d_in[4];
    const float* b_post = (const float*)d_in[5];
    float* out = (float*)d_out;

    char* ws = (char*)d_ws;
    _Float16* h16 = (_Float16*)(ws + WS_H16);
    _Float16* x16 = (_Float16*)(ws + WS_X16);
    _Float16* w16 = (_Float16*)(ws + WS_W16);
    float*    su  = (float*)   (ws + WS_SU);

    setup_kernel<<<1281, 256, 0, stream>>>(x, W_pre, qw, x16, w16, su);
    dim3 g1(MBATCH / 128, DIM / 64);
    gemm16_kernel<<<g1, 256, 0, stream>>>(x16, w16, b_pre, h16);
    quantum_kernel<<<MBATCH / 8, dim3(64, 4), 0, stream>>>(h16, su, W_post, b_post, out);
}

// Round 6
// 69.726 us; speedup vs baseline: 2.2495x; 2.2495x over previous
//
#include <hip/hip_runtime.h>
#include <hip/hip_bf16.h>
#include <math.h>

#define NQ   10
#define DIM  1024     // 2^NQ
#define NL   4
#define INF  512
#define OUTF 64
#define MBATCH 4096

typedef _Float16 half8 __attribute__((ext_vector_type(8)));
typedef float f32x4 __attribute__((ext_vector_type(4)));
typedef float f32x2 __attribute__((ext_vector_type(2)));

// ws layout (bytes)
#define WS_H16  0
#define WS_X16  (8u * 1024u * 1024u)
#define WS_W16  (12u * 1024u * 1024u)
#define WS_SU   (13u * 1024u * 1024u)

#if __has_builtin(__builtin_amdgcn_permlane32_swap)
#define HAVE_PL32 1
#else
#define HAVE_PL32 0
#endif
#if __has_builtin(__builtin_amdgcn_permlane16_swap)
#define HAVE_PL16 1
#else
#define HAVE_PL16 0
#endif

// ===========================================================================
// Compile-time GF(2) layout tracking (verified rounds 4-5).
// ===========================================================================
constexpr int fstep(int j, int r) {
    for (int w2 = NQ - 1; w2 >= 0; --w2) {
        const int cb = 9 - w2;
        const int tb = 9 - ((w2 + r) % NQ);
        j ^= ((j >> cb) & 1) << tb;
    }
    return j;
}
constexpr int ifstep(int j, int r) {
    for (int w2 = 0; w2 < NQ; ++w2) {
        const int cb = 9 - w2;
        const int tb = 9 - ((w2 + r) % NQ);
        j ^= ((j >> cb) & 1) << tb;
    }
    return j;
}
constexpr int sigma_fwd(int l, int x) {
    for (int t = l - 1; t >= 0; --t) x = fstep(x, t + 1);
    return x;
}
constexpr int sigma_inv(int l, int s) {
    for (int t = 0; t < l; ++t) s = ifstep(s, t + 1);
    return s;
}
constexpr int gate_m(int l, int b) { return sigma_fwd(l, 1 << b); }
constexpr int gate_g(int l, int b) {
    int g = 0;
    for (int j = 0; j < NQ; ++j)
        if ((sigma_inv(l, 1 << j) >> b) & 1) g |= 1 << j;
    return g;
}
struct QM { int v[NQ]; };
constexpr QM make_qm() {
    QM q{};
    for (int w = 0; w < NQ; ++w) {
        const int B = 9 - w;
        int m = 0;
        for (int j = 0; j < NQ; ++j)
            if ((sigma_inv(NL, 1 << j) >> B) & 1) m |= 1 << j;
        q.v[w] = m;
    }
    return q;
}
constexpr QM QMASKS = make_qm();

// ===========================================================================
// Setup + GEMM (unchanged, verified rounds 3-5)
// ===========================================================================
__global__ __launch_bounds__(256) void setup_kernel(
    const float* __restrict__ x, const float* __restrict__ w,
    const float* __restrict__ qw, _Float16* __restrict__ x16,
    _Float16* __restrict__ w16, float* __restrict__ su)
{
    const int bid = blockIdx.x;
    const int tid = threadIdx.x;
    if (bid < 1024) {
        const int base = bid * 2048 + tid * 8;
        float4 a = *reinterpret_cast<const float4*>(x + base);
        float4 b = *reinterpret_cast<const float4*>(x + base + 4);
        half8 o = {(_Float16)a.x, (_Float16)a.y, (_Float16)a.z, (_Float16)a.w,
                   (_Float16)b.x, (_Float16)b.y, (_Float16)b.z, (_Float16)b.w};
        *reinterpret_cast<half8*>(x16 + base) = o;
    } else if (bid < 1280) {
        const int base = (bid - 1024) * 2048 + tid * 8;
        float4 a = *reinterpret_cast<const float4*>(w + base);
        float4 b = *reinterpret_cast<const float4*>(w + base + 4);
        half8 o = {(_Float16)a.x, (_Float16)a.y, (_Float16)a.z, (_Float16)a.w,
                   (_Float16)b.x, (_Float16)b.y, (_Float16)b.z, (_Float16)b.w};
        *reinterpret_cast<half8*>(w16 + base) = o;
    } else {
        if (tid < NL * NQ) {
            float phi = qw[tid * 3 + 0], theta = qw[tid * 3 + 1], omega = qw[tid * 3 + 2];
            float st, ct; sincosf(0.5f * theta, &st, &ct);
            float spm, cpm; sincosf(0.5f * (phi - omega), &spm, &cpm);
            float spp, cpp; sincosf(0.5f * (phi + omega), &spp, &cpp);
            float* o = su + tid * 8;
            o[0] =  cpp * ct; o[1] = -spp * ct;
            o[2] = -cpm * st; o[3] = -spm * st;
            o[4] =  cpm * st; o[5] = -spm * st;
            o[6] =  cpp * ct; o[7] =  spp * ct;
        }
    }
}

__global__ __launch_bounds__(256) void gemm16_kernel(
    const _Float16* __restrict__ X, const _Float16* __restrict__ W,
    const float* __restrict__ bias, _Float16* __restrict__ H)
{
    constexpr int BM = 128, BN = 64, BK = 32, LDP = BK + 8;
    __shared__ _Float16 As[BM][LDP];
    __shared__ _Float16 Bs[BN][LDP];

    const int tid = threadIdx.x;
    const int wave = tid >> 6, lane = tid & 63;
    const int wm = wave >> 1, wn = wave & 1;
    const int l15 = lane & 15, lk = (lane >> 4) * 8;

    const int arow = tid >> 1, ahalf = tid & 1;
    const int brow = tid & 63, bseg = tid >> 6;

    const _Float16* ag = X + (size_t)(blockIdx.x * BM + arow) * INF + ahalf * 16;
    const _Float16* bg = W + (size_t)(blockIdx.y * BN + brow) * INF + bseg * 8;

    f32x4 acc[4][2] = {};

    for (int k0 = 0; k0 < INF; k0 += BK) {
        half8 av0 = *reinterpret_cast<const half8*>(ag + k0);
        half8 av1 = *reinterpret_cast<const half8*>(ag + k0 + 8);
        half8 bv  = *reinterpret_cast<const half8*>(bg + k0);
        __syncthreads();
        *reinterpret_cast<half8*>(&As[arow][ahalf * 16])     = av0;
        *reinterpret_cast<half8*>(&As[arow][ahalf * 16 + 8]) = av1;
        *reinterpret_cast<half8*>(&Bs[brow][bseg * 8])       = bv;
        __syncthreads();
        half8 bfr0 = *reinterpret_cast<const half8*>(&Bs[wn * 32 + l15][lk]);
        half8 bfr1 = *reinterpret_cast<const half8*>(&Bs[wn * 32 + 16 + l15][lk]);
#pragma unroll
        for (int mi = 0; mi < 4; ++mi) {
            half8 afr = *reinterpret_cast<const half8*>(&As[wm * 64 + mi * 16 + l15][lk]);
            acc[mi][0] = __builtin_amdgcn_mfma_f32_16x16x32_f16(afr, bfr0, acc[mi][0], 0, 0, 0);
            acc[mi][1] = __builtin_amdgcn_mfma_f32_16x16x32_f16(afr, bfr1, acc[mi][1], 0, 0, 0);
        }
    }

    const int crow0 = blockIdx.x * BM + wm * 64;
    const int ccol0 = blockIdx.y * BN + wn * 32;
#pragma unroll
    for (int ni = 0; ni < 2; ++ni) {
        const int col = ccol0 + ni * 16 + l15;
        const float bb = bias[col];
#pragma unroll
        for (int mi = 0; mi < 4; ++mi) {
#pragma unroll
            for (int r = 0; r < 4; ++r) {
                const int row = crow0 + mi * 16 + (lane >> 4) * 4 + r;
                const float o = fmaxf(acc[mi][ni][r] + bb, 0.f);
                H[(size_t)row * DIM + col] = (_Float16)o;
            }
        }
    }
}

// ===========================================================================
// Cross-lane xor exchange, compile-time routed (correctness verified round 5):
//   DPP: {1,2,3,7,8,15}; permlane16/32_swap for 16/32/48 + DPP residue;
//   ds_swizzle: other masks <32; ds_bpermute: the rest.
// ===========================================================================
constexpr bool dpp_ok(int m) {
    return m == 0 || m == 1 || m == 2 || m == 3 || m == 7 || m == 8 || m == 15;
}
constexpr int dpp_ctrl(int m) {
    return m == 1 ? 0xB1 : m == 2 ? 0x4E : m == 3 ? 0x1B :
           m == 7 ? 0x141 : m == 8 ? 0x128 : 0x140;   // 15 -> row_mirror
}

template<int MHI>
__device__ __forceinline__ int lxi(int v, int lane) {
    if constexpr (MHI == 0)
        return v;
    else if constexpr (dpp_ok(MHI))
        return __builtin_amdgcn_mov_dpp(v, dpp_ctrl(MHI), 0xF, 0xF, false);
#if HAVE_PL32
    else if constexpr ((MHI & 32) && dpp_ok(MHI & 15)) {
        auto q = __builtin_amdgcn_permlane32_swap(v, v, false, false);
        const int r = (lane & 32) ? q[0] : q[1];
        return lxi<MHI & 31>(r, lane);
    }
#endif
#if HAVE_PL16
    else if constexpr ((MHI & 16) && dpp_ok(MHI & 15)) {
        auto q = __builtin_amdgcn_permlane16_swap(v, v, false, false);
        const int r = (lane & 16) ? q[0] : q[1];
        return lxi<MHI & 15>(r, lane);
    }
#endif
    else if constexpr (MHI < 32)
        return __builtin_amdgcn_ds_swizzle(v, 0x1F | (MHI << 10));
    else
        return __builtin_amdgcn_ds_bpermute((lane ^ MHI) << 2, v);
}

template<int MHI>
__device__ __forceinline__ float lxf(float v, int lane) {
    return __int_as_float(lxi<MHI>(__float_as_int(v), lane));
}

// butterfly allreduce (sum) across 64 lanes via cheapest exchanges
__device__ __forceinline__ float allred(float v, int lane) {
    v += lxf<1>(v, lane);
    v += lxf<2>(v, lane);
    v += lxf<4>(v, lane);
    v += lxf<8>(v, lane);
    v += lxf<16>(v, lane);
    v += lxf<32>(v, lane);
    return v;
}

// ===========================================================================
// One gate (layer L, wire W). State rr/ii[8] f32x2 (amp k: bit0 selects
// .x/.y). Structure verified round 4.
// ===========================================================================
template<int L, int W>
__device__ __forceinline__ void apply_gate(f32x2 rr[8], f32x2 ii[8],
                                           const float* __restrict__ su, int lane)
{
    constexpr int b   = 9 - W;
    constexpr int m   = gate_m(L, b);
    constexpr int g   = gate_g(L, b);
    constexpr int MHI = m >> 4, MLO = m & 15;
    constexpr int GHI = g >> 4, GLO = g & 15;

    const float4 ua = *reinterpret_cast<const float4*>(su + (L * NQ + W) * 8);
    const float4 ub = *reinterpret_cast<const float4*>(su + (L * NQ + W) * 8 + 4);
    const bool hl = __builtin_popcount(lane & GHI) & 1;

    const float cmr0 = hl ? ub.z : ua.x, cmi0 = hl ? ub.w : ua.y;
    const float cpr0 = hl ? ub.x : ua.z, cpi0 = hl ? ub.y : ua.w;
    const float cmr1 = hl ? ua.x : ub.z, cmi1 = hl ? ua.y : ub.w;
    const float cpr1 = hl ? ua.z : ub.x, cpi1 = hl ? ua.w : ub.y;

    float pr[16], pi[16];
#pragma unroll
    for (int k = 0; k < 16; ++k) {
        const int kp = k ^ MLO;
        const float vr = (kp & 1) ? rr[kp >> 1].y : rr[kp >> 1].x;
        const float vi = (kp & 1) ? ii[kp >> 1].y : ii[kp >> 1].x;
        pr[k] = lxf<MHI>(vr, lane);
        pi[k] = lxf<MHI>(vi, lane);
    }
#pragma unroll
    for (int j = 0; j < 8; ++j) {
        const int k0 = 2 * j, k1 = 2 * j + 1;
        const int h0 = __builtin_popcount(k0 & GLO) & 1;   // compile-time
        const int h1 = __builtin_popcount(k1 & GLO) & 1;
        f32x2 CMR, CMI, CPR, CPI, PR, PI;
        CMR.x = h0 ? cmr1 : cmr0;  CMR.y = h1 ? cmr1 : cmr0;
        CMI.x = h0 ? cmi1 : cmi0;  CMI.y = h1 ? cmi1 : cmi0;
        CPR.x = h0 ? cpr1 : cpr0;  CPR.y = h1 ? cpr1 : cpr0;
        CPI.x = h0 ? cpi1 : cpi0;  CPI.y = h1 ? cpi1 : cpi0;
        PR.x = pr[k0]; PR.y = pr[k1];
        PI.x = pi[k0]; PI.y = pi[k1];
        const f32x2 R = rr[j], I = ii[j];
        rr[j] = R * CMR - I * CMI + PR * CPR - PI * CPI;
        ii[j] = I * CMR + R * CMI + PI * CPR + PR * CPI;
    }
}

template<int L>
__device__ __forceinline__ void apply_layer(f32x2 rr[8], f32x2 ii[8],
                                            const float* __restrict__ su, int lane)
{
    apply_gate<L, 0>(rr, ii, su, lane);
    apply_gate<L, 1>(rr, ii, su, lane);
    apply_gate<L, 2>(rr, ii, su, lane);
    apply_gate<L, 3>(rr, ii, su, lane);
    apply_gate<L, 4>(rr, ii, su, lane);
    apply_gate<L, 5>(rr, ii, su, lane);
    apply_gate<L, 6>(rr, ii, su, lane);
    apply_gate<L, 7>(rr, ii, su, lane);
    apply_gate<L, 8>(rr, ii, su, lane);
    apply_gate<L, 9>(rr, ii, su, lane);
}

// ===========================================================================
// Kernel 2: ONE wave per batch row (4096 waves = full latency-hiding
// occupancy; round-5 lesson: never trade wave count away). No LDS state.
// ===========================================================================
__global__ __launch_bounds__(256) void quantum_kernel(
    const _Float16* __restrict__ Hbuf, const float* __restrict__ sug,
    const float* __restrict__ W_post, const float* __restrict__ b_post,
    float* __restrict__ out)
{
    const int lane = threadIdx.x;
    const int row  = blockIdx.x * 4 + threadIdx.y;

    // --- load row (f16); amp index i = (lane<<4) | k
    const _Float16* hr = Hbuf + (size_t)row * DIM + (lane << 4);
    f32x2 rr[8], ii[8];
    {
        half8 h0 = *reinterpret_cast<const half8*>(hr);
        half8 h1 = *reinterpret_cast<const half8*>(hr + 8);
#pragma unroll
        for (int j = 0; j < 4; ++j) {
            rr[j].x     = (float)h0[2 * j]; rr[j].y     = (float)h0[2 * j + 1];
            rr[j + 4].x = (float)h1[2 * j]; rr[j + 4].y = (float)h1[2 * j + 1];
            ii[j]     = f32x2{0.f, 0.f};
            ii[j + 4] = f32x2{0.f, 0.f};
        }
    }
    f32x2 n2 = f32x2{0.f, 0.f};
#pragma unroll
    for (int j = 0; j < 8; ++j) n2 += rr[j] * rr[j];
    const float inv_nrm = 1.0f / allred(n2.x + n2.y, lane);

    // --- circuit (layout-tracked; permutations are free)
    apply_layer<0>(rr, ii, sug, lane);
    apply_layer<1>(rr, ii, sug, lane);
    apply_layer<2>(rr, ii, sug, lane);
    apply_layer<3>(rr, ii, sug, lane);

    // --- probabilities
    f32x2 P[8];
#pragma unroll
    for (int j = 0; j < 8; ++j) P[j] = rr[j] * rr[j] + ii[j] * ii[j];

    // --- PauliZ expvals with layout-adjusted sign masks
    float z[NQ];
#pragma unroll
    for (int w = 0; w < NQ; ++w) {
        const int q = QMASKS.v[w];
        const int qhi = q >> 4, qlo = q & 15;
        float zl = 0.f;
#pragma unroll
        for (int j = 0; j < 8; ++j) {
            const float s0 = (__builtin_popcount((2 * j) & qlo) & 1) ? -1.f : 1.f;
            const float s1 = (__builtin_popcount((2 * j + 1) & qlo) & 1) ? -1.f : 1.f;
            zl += s0 * P[j].x;
            zl += s1 * P[j].y;
        }
        if (__builtin_popcount(lane & qhi) & 1) zl = -zl;
        z[w] = allred(zl, lane) * inv_nrm;
    }

    // --- post-GEMM: out[row*64 + lane]
    float o = b_post[lane];
#pragma unroll
    for (int w = 0; w < NQ; ++w)
        o = fmaf(z[w], W_post[lane * NQ + w], o);
    out[(size_t)row * OUTF + lane] = o;
}

extern "C" void kernel_launch(void* const* d_in, const int* in_sizes, int n_in,
                              void* d_out, int out_size, void* d_ws, size_t ws_size,
                              hipStream_t stream) {
    const float* x      = (const float*)d_in[0];
    const float* W_pre  = (const float*)d_in[1];
    const float* b_pre  = (const float*)d_in[2];
    const float* qw     = (const float*)d_in[3];
    const float* W_post = (const float*)d_in[4];
    const float* b_post = (const float*)d_in[5];
    float* out = (float*)d_out;

    char* ws = (char*)d_ws;
    _Float16* h16 = (_Float16*)(ws + WS_H16);
    _Float16* x16 = (_Float16*)(ws + WS_X16);
    _Float16* w16 = (_Float16*)(ws + WS_W16);
    float*    su  = (float*)   (ws + WS_SU);

    setup_kernel<<<1281, 256, 0, stream>>>(x, W_pre, qw, x16, w16, su);
    dim3 g1(MBATCH / 128, DIM / 64);
    gemm16_kernel<<<g1, 256, 0, stream>>>(x16, w16, b_pre, h16);
    quantum_kernel<<<MBATCH / 4, dim3(64, 4), 0, stream>>>(h16, su, W_post, b_post, out);
}

// Round 7
// 64.863 us; speedup vs baseline: 2.4181x; 1.0750x over previous
//
#include <hip/hip_runtime.h>
#include <hip/hip_bf16.h>
#include <math.h>

#define NQ   10
#define DIM  1024     // 2^NQ
#define NL   4
#define INF  512
#define OUTF 64
#define MBATCH 4096

typedef _Float16 half8 __attribute__((ext_vector_type(8)));
typedef float f32x4 __attribute__((ext_vector_type(4)));
typedef float f32x2 __attribute__((ext_vector_type(2)));

// ws layout (bytes)
#define WS_H16  0
#define WS_X16  (8u * 1024u * 1024u)
#define WS_W16  (12u * 1024u * 1024u)
#define WS_SU   (13u * 1024u * 1024u)

// ===========================================================================
// Compile-time GF(2) layout tracking (verified rounds 4-6).
// ===========================================================================
constexpr int fstep(int j, int r) {
    for (int w2 = NQ - 1; w2 >= 0; --w2) {
        const int cb = 9 - w2;
        const int tb = 9 - ((w2 + r) % NQ);
        j ^= ((j >> cb) & 1) << tb;
    }
    return j;
}
constexpr int ifstep(int j, int r) {
    for (int w2 = 0; w2 < NQ; ++w2) {
        const int cb = 9 - w2;
        const int tb = 9 - ((w2 + r) % NQ);
        j ^= ((j >> cb) & 1) << tb;
    }
    return j;
}
constexpr int sigma_fwd(int l, int x) {
    for (int t = l - 1; t >= 0; --t) x = fstep(x, t + 1);
    return x;
}
constexpr int sigma_inv(int l, int s) {
    for (int t = 0; t < l; ++t) s = ifstep(s, t + 1);
    return s;
}
constexpr int gate_m(int l, int b) { return sigma_fwd(l, 1 << b); }
constexpr int gate_g(int l, int b) {
    int g = 0;
    for (int j = 0; j < NQ; ++j)
        if ((sigma_inv(l, 1 << j) >> b) & 1) g |= 1 << j;
    return g;
}
struct QM { int v[NQ]; };
constexpr QM make_qm() {
    QM q{};
    for (int w = 0; w < NQ; ++w) {
        const int B = 9 - w;
        int m = 0;
        for (int j = 0; j < NQ; ++j)
            if ((sigma_inv(NL, 1 << j) >> B) & 1) m |= 1 << j;
        q.v[w] = m;
    }
    return q;
}
constexpr QM QMASKS = make_qm();

// ===========================================================================
// Hardware-coordinate assignment: slot bits 0..2 = reg (k), one bit = wave,
// remaining 6 bits = lane.  Wave bit chosen to minimize cross-wave gates.
// ===========================================================================
constexpr int mask_at(int t) { return gate_m(t / 10, 9 - (t % 10)); }
constexpr int pick_wbit() {
    int best = 9, bc = 1000;
    for (int j = 3; j <= 9; ++j) {
        int c = 0;
        for (int t = 0; t < 40; ++t) c += (mask_at(t) >> j) & 1;
        if (c < bc) { bc = c; best = j; }
    }
    return best;
}
constexpr int WBIT = pick_wbit();
struct LP { int v[6]; };
constexpr LP make_lpos() {
    LP p{}; int n = 0;
    for (int j = 3; j <= 9; ++j) if (j != WBIT) p.v[n++] = j;
    return p;
}
constexpr LP LPOS = make_lpos();
constexpr int lx_extract(int m) {
    int r = 0;
    for (int t = 0; t < 6; ++t) if ((m >> LPOS.v[t]) & 1) r |= 1 << t;
    return r;
}

// ===========================================================================
// Setup + GEMM (unchanged, verified rounds 3-6)
// ===========================================================================
__global__ __launch_bounds__(256) void setup_kernel(
    const float* __restrict__ x, const float* __restrict__ w,
    const float* __restrict__ qw, _Float16* __restrict__ x16,
    _Float16* __restrict__ w16, float* __restrict__ su)
{
    const int bid = blockIdx.x;
    const int tid = threadIdx.x;
    if (bid < 1024) {
        const int base = bid * 2048 + tid * 8;
        float4 a = *reinterpret_cast<const float4*>(x + base);
        float4 b = *reinterpret_cast<const float4*>(x + base + 4);
        half8 o = {(_Float16)a.x, (_Float16)a.y, (_Float16)a.z, (_Float16)a.w,
                   (_Float16)b.x, (_Float16)b.y, (_Float16)b.z, (_Float16)b.w};
        *reinterpret_cast<half8*>(x16 + base) = o;
    } else if (bid < 1280) {
        const int base = (bid - 1024) * 2048 + tid * 8;
        float4 a = *reinterpret_cast<const float4*>(w + base);
        float4 b = *reinterpret_cast<const float4*>(w + base + 4);
        half8 o = {(_Float16)a.x, (_Float16)a.y, (_Float16)a.z, (_Float16)a.w,
                   (_Float16)b.x, (_Float16)b.y, (_Float16)b.z, (_Float16)b.w};
        *reinterpret_cast<half8*>(w16 + base) = o;
    } else {
        if (tid < NL * NQ) {
            float phi = qw[tid * 3 + 0], theta = qw[tid * 3 + 1], omega = qw[tid * 3 + 2];
            float st, ct; sincosf(0.5f * theta, &st, &ct);
            float spm, cpm; sincosf(0.5f * (phi - omega), &spm, &cpm);
            float spp, cpp; sincosf(0.5f * (phi + omega), &spp, &cpp);
            float* o = su + tid * 8;
            o[0] =  cpp * ct; o[1] = -spp * ct;
            o[2] = -cpm * st; o[3] = -spm * st;
            o[4] =  cpm * st; o[5] = -spm * st;
            o[6] =  cpp * ct; o[7] =  spp * ct;
        }
    }
}

__global__ __launch_bounds__(256) void gemm16_kernel(
    const _Float16* __restrict__ X, const _Float16* __restrict__ W,
    const float* __restrict__ bias, _Float16* __restrict__ H)
{
    constexpr int BM = 128, BN = 64, BK = 32, LDP = BK + 8;
    __shared__ _Float16 As[BM][LDP];
    __shared__ _Float16 Bs[BN][LDP];

    const int tid = threadIdx.x;
    const int wave = tid >> 6, lane = tid & 63;
    const int wm = wave >> 1, wn = wave & 1;
    const int l15 = lane & 15, lk = (lane >> 4) * 8;

    const int arow = tid >> 1, ahalf = tid & 1;
    const int brow = tid & 63, bseg = tid >> 6;

    const _Float16* ag = X + (size_t)(blockIdx.x * BM + arow) * INF + ahalf * 16;
    const _Float16* bg = W + (size_t)(blockIdx.y * BN + brow) * INF + bseg * 8;

    f32x4 acc[4][2] = {};

    for (int k0 = 0; k0 < INF; k0 += BK) {
        half8 av0 = *reinterpret_cast<const half8*>(ag + k0);
        half8 av1 = *reinterpret_cast<const half8*>(ag + k0 + 8);
        half8 bv  = *reinterpret_cast<const half8*>(bg + k0);
        __syncthreads();
        *reinterpret_cast<half8*>(&As[arow][ahalf * 16])     = av0;
        *reinterpret_cast<half8*>(&As[arow][ahalf * 16 + 8]) = av1;
        *reinterpret_cast<half8*>(&Bs[brow][bseg * 8])       = bv;
        __syncthreads();
        half8 bfr0 = *reinterpret_cast<const half8*>(&Bs[wn * 32 + l15][lk]);
        half8 bfr1 = *reinterpret_cast<const half8*>(&Bs[wn * 32 + 16 + l15][lk]);
#pragma unroll
        for (int mi = 0; mi < 4; ++mi) {
            half8 afr = *reinterpret_cast<const half8*>(&As[wm * 64 + mi * 16 + l15][lk]);
            acc[mi][0] = __builtin_amdgcn_mfma_f32_16x16x32_f16(afr, bfr0, acc[mi][0], 0, 0, 0);
            acc[mi][1] = __builtin_amdgcn_mfma_f32_16x16x32_f16(afr, bfr1, acc[mi][1], 0, 0, 0);
        }
    }

    const int crow0 = blockIdx.x * BM + wm * 64;
    const int ccol0 = blockIdx.y * BN + wn * 32;
#pragma unroll
    for (int ni = 0; ni < 2; ++ni) {
        const int col = ccol0 + ni * 16 + l15;
        const float bb = bias[col];
#pragma unroll
        for (int mi = 0; mi < 4; ++mi) {
#pragma unroll
            for (int r = 0; r < 4; ++r) {
                const int row = crow0 + mi * 16 + (lane >> 4) * 4 + r;
                const float o = fmaxf(acc[mi][ni][r] + bb, 0.f);
                H[(size_t)row * DIM + col] = (_Float16)o;
            }
        }
    }
}

// ===========================================================================
// Cross-lane xor exchange — round-4 routing exactly (round-6 lesson:
// permlane+cndmask on the VALU pipe loses to ds_swizzle on the DS pipe).
// ===========================================================================
template<int MHI>
__device__ __forceinline__ int lxi(int v, int lane) {
    if constexpr (MHI == 0)
        return v;
    else if constexpr (MHI == 1)
        return __builtin_amdgcn_mov_dpp(v, 0xB1, 0xF, 0xF, false);
    else if constexpr (MHI == 2)
        return __builtin_amdgcn_mov_dpp(v, 0x4E, 0xF, 0xF, false);
    else if constexpr (MHI == 3)
        return __builtin_amdgcn_mov_dpp(v, 0x1B, 0xF, 0xF, false);
    else if constexpr (MHI == 8)
        return __builtin_amdgcn_mov_dpp(v, 0x128, 0xF, 0xF, false);
    else if constexpr (MHI < 32)
        return __builtin_amdgcn_ds_swizzle(v, 0x1F | (MHI << 10));
    else
        return __builtin_amdgcn_ds_bpermute((lane ^ MHI) << 2, v);
}

template<int MHI>
__device__ __forceinline__ float lxf(float v, int lane) {
    return __int_as_float(lxi<MHI>(__float_as_int(v), lane));
}

__device__ __forceinline__ float allred(float v, int lane) {
    v += lxf<1>(v, lane);
    v += lxf<2>(v, lane);
    v += lxf<4>(v, lane);
    v += lxf<8>(v, lane);
    v += lxf<16>(v, lane);
    v += lxf<32>(v, lane);
    return v;
}

// ===========================================================================
// One gate (layer L, wire W); 8 amps/thread. Amp k (3 bits): bit0 -> .x/.y
// of f32x2 pair j=k>>1. Slot = wave@WBIT | lane@LPOS | k@bits2..0.
// Cross-wave gates (mask hits WBIT) go through a conflict-free plane-major
// LDS round trip; everything else is in-wave (reg-local or lane exchange).
// ===========================================================================
template<int L, int W>
__device__ __forceinline__ void apply_gate(f32x2 rr[4], f32x2 ii[4],
                                           const float* __restrict__ su,
                                           int lane, int wave,
                                           f32x4 (*buf)[2][64])
{
    constexpr int b = 9 - W;
    constexpr int m = gate_m(L, b);
    constexpr int g = gate_g(L, b);
    constexpr int MW    = (m >> WBIT) & 1;
    constexpr int MLANE = lx_extract(m);
    constexpr int MREG  = m & 7;
    constexpr int GW    = (g >> WBIT) & 1;
    constexpr int GLANE = lx_extract(g);
    constexpr int GREG  = g & 7;

    const float4 ua = *reinterpret_cast<const float4*>(su + (L * NQ + W) * 8);
    const float4 ub = *reinterpret_cast<const float4*>(su + (L * NQ + W) * 8 + 4);
    int hli = __builtin_popcount(lane & GLANE) & 1;
    if constexpr (GW) hli ^= wave;
    const bool hl = hli != 0;

    const float cmr0 = hl ? ub.z : ua.x, cmi0 = hl ? ub.w : ua.y;
    const float cpr0 = hl ? ub.x : ua.z, cpi0 = hl ? ub.y : ua.w;
    const float cmr1 = hl ? ua.x : ub.z, cmi1 = hl ? ua.y : ub.w;
    const float cpr1 = hl ? ua.z : ub.x, cpi1 = hl ? ua.w : ub.y;

    float pr[8], pi[8];
    if constexpr (MW == 0) {
#pragma unroll
        for (int k = 0; k < 8; ++k) {
            const int kp = k ^ MREG;
            const float vr = (kp & 1) ? rr[kp >> 1].y : rr[kp >> 1].x;
            const float vi = (kp & 1) ? ii[kp >> 1].y : ii[kp >> 1].x;
            pr[k] = lxf<MLANE>(vr, lane);
            pi[k] = lxf<MLANE>(vi, lane);
        }
    } else {
        // plane-major: each b128 op covers a contiguous 1 KB => conflict-free
        buf[0][wave][lane] = f32x4{rr[0].x, rr[0].y, rr[1].x, rr[1].y};
        buf[1][wave][lane] = f32x4{rr[2].x, rr[2].y, rr[3].x, rr[3].y};
        buf[2][wave][lane] = f32x4{ii[0].x, ii[0].y, ii[1].x, ii[1].y};
        buf[3][wave][lane] = f32x4{ii[2].x, ii[2].y, ii[3].x, ii[3].y};
        __syncthreads();
        const int pl = lane ^ MLANE;
        const int pw = wave ^ 1;
        const f32x4 R0 = buf[0][pw][pl];
        const f32x4 R1 = buf[1][pw][pl];
        const f32x4 I0 = buf[2][pw][pl];
        const f32x4 I1 = buf[3][pw][pl];
        __syncthreads();   // reads done before any later reuse of buf
#pragma unroll
        for (int k = 0; k < 8; ++k) {
            const int kp = k ^ MREG;
            pr[k] = (kp & 4) ? R1[kp & 3] : R0[kp & 3];
            pi[k] = (kp & 4) ? I1[kp & 3] : I0[kp & 3];
        }
    }
#pragma unroll
    for (int j = 0; j < 4; ++j) {
        const int k0 = 2 * j, k1 = 2 * j + 1;
        const int h0 = __builtin_popcount(k0 & GREG) & 1;   // compile-time
        const int h1 = __builtin_popcount(k1 & GREG) & 1;
        f32x2 CMR, CMI, CPR, CPI, PR, PI;
        CMR.x = h0 ? cmr1 : cmr0;  CMR.y = h1 ? cmr1 : cmr0;
        CMI.x = h0 ? cmi1 : cmi0;  CMI.y = h1 ? cmi1 : cmi0;
        CPR.x = h0 ? cpr1 : cpr0;  CPR.y = h1 ? cpr1 : cpr0;
        CPI.x = h0 ? cpi1 : cpi0;  CPI.y = h1 ? cpi1 : cpi0;
        PR.x = pr[k0]; PR.y = pr[k1];
        PI.x = pi[k0]; PI.y = pi[k1];
        const f32x2 R = rr[j], I = ii[j];
        rr[j] = R * CMR - I * CMI + PR * CPR - PI * CPI;
        ii[j] = I * CMR + R * CMI + PI * CPR + PR * CPI;
    }
}

template<int L>
__device__ __forceinline__ void apply_layer(f32x2 rr[4], f32x2 ii[4],
                                            const float* __restrict__ su,
                                            int lane, int wave,
                                            f32x4 (*buf)[2][64])
{
    apply_gate<L, 0>(rr, ii, su, lane, wave, buf);
    apply_gate<L, 1>(rr, ii, su, lane, wave, buf);
    apply_gate<L, 2>(rr, ii, su, lane, wave, buf);
    apply_gate<L, 3>(rr, ii, su, lane, wave, buf);
    apply_gate<L, 4>(rr, ii, su, lane, wave, buf);
    apply_gate<L, 5>(rr, ii, su, lane, wave, buf);
    apply_gate<L, 6>(rr, ii, su, lane, wave, buf);
    apply_gate<L, 7>(rr, ii, su, lane, wave, buf);
    apply_gate<L, 8>(rr, ii, su, lane, wave, buf);
    apply_gate<L, 9>(rr, ii, su, lane, wave, buf);
}

// ===========================================================================
// Kernel 2: TWO waves per batch row (8192 waves = 8/SIMD), 8 amps/thread.
// ===========================================================================
__global__ __launch_bounds__(128, 8) void quantum_kernel(
    const _Float16* __restrict__ Hbuf, const float* __restrict__ sug,
    const float* __restrict__ W_post, const float* __restrict__ b_post,
    float* __restrict__ out)
{
    __shared__ f32x4 buf[4][2][64];   // 8 KB cross-wave exchange buffer
    __shared__ float sred[34];        // [0..31] z partials, [32..33] norm

    const int lane = threadIdx.x;     // 0..63
    const int wave = threadIdx.y;     // 0..1
    const int row  = blockIdx.x;

    // storage-slot base for this thread (bits: wave@WBIT, lane@LPOS, k@0..2)
    int pb = wave << WBIT;
#pragma unroll
    for (int t = 0; t < 6; ++t) pb |= ((lane >> t) & 1) << LPOS.v[t];

    // --- load 8 amps (f16, contiguous b128)
    const _Float16* hr = Hbuf + (size_t)row * DIM + pb;
    f32x2 rr[4], ii[4];
    {
        half8 h0 = *reinterpret_cast<const half8*>(hr);
#pragma unroll
        for (int j = 0; j < 4; ++j) {
            rr[j].x = (float)h0[2 * j]; rr[j].y = (float)h0[2 * j + 1];
            ii[j] = f32x2{0.f, 0.f};
        }
    }

    // --- squared norm: in-wave allreduce + cross-wave combine
    f32x2 n2 = f32x2{0.f, 0.f};
#pragma unroll
    for (int j = 0; j < 4; ++j) n2 += rr[j] * rr[j];
    float nw = allred(n2.x + n2.y, lane);
    if (lane == 0) sred[32 + wave] = nw;
    __syncthreads();
    const float inv_nrm = 1.0f / (sred[32] + sred[33]);

    // --- circuit (layout-tracked; CNOT permutations free)
    apply_layer<0>(rr, ii, sug, lane, wave, buf);
    apply_layer<1>(rr, ii, sug, lane, wave, buf);
    apply_layer<2>(rr, ii, sug, lane, wave, buf);
    apply_layer<3>(rr, ii, sug, lane, wave, buf);

    // --- probabilities
    f32x2 P[4];
#pragma unroll
    for (int j = 0; j < 4; ++j) P[j] = rr[j] * rr[j] + ii[j] * ii[j];

    // --- PauliZ expvals with layout-adjusted sign masks
    float z[NQ];
#pragma unroll
    for (int w = 0; w < NQ; ++w) {
        const int q = QMASKS.v[w];
        const int qw_ = (q >> WBIT) & 1;
        const int qlane = lx_extract(q);
        const int qreg = q & 7;
        float zl = 0.f;
#pragma unroll
        for (int j = 0; j < 4; ++j) {
            const float s0 = (__builtin_popcount((2 * j) & qreg) & 1) ? -1.f : 1.f;
            const float s1 = (__builtin_popcount((2 * j + 1) & qreg) & 1) ? -1.f : 1.f;
            zl += s0 * P[j].x + s1 * P[j].y;
        }
        int neg = __builtin_popcount(lane & qlane) & 1;
        neg ^= (wave & qw_);
        if (neg) zl = -zl;
        z[w] = allred(zl, lane);
    }
    if (lane == 0) {
#pragma unroll
        for (int w = 0; w < NQ; ++w) sred[wave * 16 + w] = z[w];
    }
    __syncthreads();

    // --- post-GEMM (wave 0 only): out[row*64 + lane]
    if (wave == 0) {
        float o = b_post[lane];
#pragma unroll
        for (int w = 0; w < NQ; ++w)
            o = fmaf((sred[w] + sred[16 + w]) * inv_nrm, W_post[lane * NQ + w], o);
        out[(size_t)row * OUTF + lane] = o;
    }
}

extern "C" void kernel_launch(void* const* d_in, const int* in_sizes, int n_in,
                              void* d_out, int out_size, void* d_ws, size_t ws_size,
                              hipStream_t stream) {
    const float* x      = (const float*)d_in[0];
    const float* W_pre  = (const float*)d_in[1];
    const float* b_pre  = (const float*)d_in[2];
    const float* qw     = (const float*)d_in[3];
    const float* W_post = (const float*)d_in[4];
    const float* b_post = (const float*)d_in[5];
    float* out = (float*)d_out;

    char* ws = (char*)d_ws;
    _Float16* h16 = (_Float16*)(ws + WS_H16);
    _Float16* x16 = (_Float16*)(ws + WS_X16);
    _Float16* w16 = (_Float16*)(ws + WS_W16);
    float*    su  = (float*)   (ws + WS_SU);

    setup_kernel<<<1281, 256, 0, stream>>>(x, W_pre, qw, x16, w16, su);
    dim3 g1(MBATCH / 128, DIM / 64);
    gemm16_kernel<<<g1, 256, 0, stream>>>(x16, w16, b_pre, h16);
    quantum_kernel<<<MBATCH, dim3(64, 2), 0, stream>>>(h16, su, W_post, b_post, out);
}